// Round 1
// baseline (565.444 us; speedup 1.0000x reference)
//
#include <hip/hip_runtime.h>
#include <stdint.h>

typedef unsigned int u32;
typedef __attribute__((ext_vector_type(8))) __bf16 bf16x8;
typedef __attribute__((ext_vector_type(8))) short s16x8;
typedef __attribute__((ext_vector_type(4))) short s16x4;
typedef __attribute__((ext_vector_type(4))) float f32x4;

// ---------- helpers ----------

__device__ __forceinline__ short f2bf(float f) {
    union { float f; u32 u; } v; v.f = f;
    u32 r = v.u + 0x7FFFu + ((v.u >> 16) & 1u);   // RNE
    return (short)(r >> 16);
}

__device__ __forceinline__ bf16x8 asbf(s16x8 v) {
    return __builtin_bit_cast(bf16x8, v);
}

// async global->LDS, 16B per lane. LDS dest = wave-uniform base + lane*16.
__device__ __forceinline__ void gl_lds16(const void* g, void* l) {
    __builtin_amdgcn_global_load_lds((__attribute__((address_space(1))) u32*)g,
                                     (__attribute__((address_space(3))) u32*)l,
                                     16, 0, 0);
}

// ---------- conversion kernel: fp32 -> bf16 for x, y, Wqkv_x, Wqkv_y, Wproj_x, Wproj_y ----------

__global__ __launch_bounds__(256) void convert_all(
    const float* __restrict__ s0, short* __restrict__ d0,
    const float* __restrict__ s1, short* __restrict__ d1,
    const float* __restrict__ s2, short* __restrict__ d2,
    const float* __restrict__ s3, short* __restrict__ d3,
    const float* __restrict__ s4, short* __restrict__ d4,
    const float* __restrict__ s5, short* __restrict__ d5)
{
    int i = blockIdx.x * 256 + threadIdx.x;   // one float4 per thread
    const float* s; short* d;
    if (i < 786432)                { s = s0; d = d0; }
    else if ((i -= 786432) < 786432) { s = s1; d = d1; }
    else if ((i -= 786432) < 442368) { s = s2; d = d2; }
    else if ((i -= 442368) < 442368) { s = s3; d = d3; }
    else if ((i -= 442368) < 147456) { s = s4; d = d4; }
    else                           { i -= 147456; s = s5; d = d5; }
    f32x4 v = ((const f32x4*)s)[i];
    s16x4 o;
    o.x = f2bf(v.x); o.y = f2bf(v.y); o.z = f2bf(v.z); o.w = f2bf(v.w);
    ((s16x4*)d)[i] = o;
}

// ---------- QKV GEMM (M=4096, N=2304, K=768) + bias + fused per-head LN ----------
// A: [4096 x 768] bf16 row-major (per stream). W: [2304 x 768] bf16 row-major.
// C[m][n] = sum_k A[m][k] * W[n][k]  (+bias). Epilogue: LN over each head's 64 cols
// for q (n<768) and k (768<=n<1536); writes Q,K as (B,H,2048,64) bf16 and V
// transposed as (B,H,64,2048) bf16.

__global__ __launch_bounds__(256, 2) void qkv_gemm(
    const short* __restrict__ Ax, const short* __restrict__ Ay,
    const short* __restrict__ Wx, const short* __restrict__ Wy,
    const float* __restrict__ biasx, const float* __restrict__ biasy,
    const float* __restrict__ gqx, const float* __restrict__ bqx,
    const float* __restrict__ gkx, const float* __restrict__ bkx,
    const float* __restrict__ gqy, const float* __restrict__ bqy,
    const float* __restrict__ gky, const float* __restrict__ bky,
    short* __restrict__ Q, short* __restrict__ K, short* __restrict__ Vt)
{
    __shared__ __align__(16) short lA[8192];   // 128x64 bf16, chunk-interleaved
    __shared__ __align__(16) short lB[8192];
    const int tid  = threadIdx.x;
    const int w    = tid >> 6, lane = tid & 63;
    const int lam  = lane & 15, quad = lane >> 4;
    const int strm = blockIdx.z;
    const short* A    = strm ? Ay : Ax;
    const short* W    = strm ? Wy : Wx;
    const float* bias = strm ? biasy : biasx;
    const int m0 = blockIdx.x * 128;
    const int n0 = blockIdx.y * 128;
    const int wm = w >> 1, wn = w & 1;

    const f32x4 fzero = {0.f, 0.f, 0.f, 0.f};
    f32x4 acc[4][4];
    #pragma unroll
    for (int i = 0; i < 4; i++)
        #pragma unroll
        for (int t = 0; t < 4; t++) acc[i][t] = fzero;

    for (int kb = 0; kb < 12; ++kb) {
        const int k0 = kb * 64;
        __syncthreads();
        // stage: chunk layout — chunk(c,ig,q,lam) holds rows[ig*16+lam], cols[k0+c*32+q*8 ..+8]
        #pragma unroll
        for (int c = 0; c < 2; c++) {
            #pragma unroll
            for (int h = 0; h < 2; h++) {
                const int ig = w + h * 4;
                gl_lds16(A + (size_t)(m0 + ig * 16 + lam) * 768 + k0 + c * 32 + quad * 8,
                         lA + (c * 8 + ig) * 512);
                gl_lds16(W + (size_t)(n0 + ig * 16 + lam) * 768 + k0 + c * 32 + quad * 8,
                         lB + (c * 8 + ig) * 512);
            }
        }
        __syncthreads();
        s16x8 af[2][4], bfr[2][4];
        #pragma unroll
        for (int c = 0; c < 2; c++)
            #pragma unroll
            for (int i = 0; i < 4; i++)
                af[c][i] = *(const s16x8*)(lA + ((c * 8 + wm * 4 + i) * 64 + lane) * 8);
        #pragma unroll
        for (int c = 0; c < 2; c++)
            #pragma unroll
            for (int t = 0; t < 4; t++)
                bfr[c][t] = *(const s16x8*)(lB + ((c * 8 + wn * 4 + t) * 64 + lane) * 8);
        #pragma unroll
        for (int c = 0; c < 2; c++)
            #pragma unroll
            for (int i = 0; i < 4; i++)
                #pragma unroll
                for (int t = 0; t < 4; t++)
                    acc[i][t] = __builtin_amdgcn_mfma_f32_16x16x32_bf16(
                        asbf(af[c][i]), asbf(bfr[c][t]), acc[i][t], 0, 0, 0);
    }

    // ---- epilogue: bias (+LN for q/k), scatter to head layouts ----
    const int nb     = n0 + wn * 64;           // 64-aligned, == one head span
    const int region = nb / 768;               // 0=q, 1=k, 2=v
    const int head   = (nb % 768) / 64;
    float bv[4];
    #pragma unroll
    for (int t = 0; t < 4; t++) bv[t] = bias[nb + t * 16 + lam];
    float gv[4], bb[4];
    if (region < 2) {
        const float* gp = (region == 0) ? (strm ? gqy : gqx) : (strm ? gky : gkx);
        const float* bp = (region == 0) ? (strm ? bqy : bqx) : (strm ? bky : bkx);
        #pragma unroll
        for (int t = 0; t < 4; t++) { gv[t] = gp[t * 16 + lam]; bb[t] = bp[t * 16 + lam]; }
    }

    #pragma unroll
    for (int i = 0; i < 4; i++) {
        #pragma unroll
        for (int reg = 0; reg < 4; reg++) {
            const int mg = m0 + wm * 64 + i * 16 + quad * 4 + reg;  // per-stream token
            const int b_ = mg >> 10;
            const int sg = (mg & 1023) + strm * 1024;
            float v0 = acc[i][0][reg] + bv[0];
            float v1 = acc[i][1][reg] + bv[1];
            float v2 = acc[i][2][reg] + bv[2];
            float v3 = acc[i][3][reg] + bv[3];
            if (region < 2) {
                float s = v0 + v1 + v2 + v3;
                s += __shfl_xor(s, 1); s += __shfl_xor(s, 2);
                s += __shfl_xor(s, 4); s += __shfl_xor(s, 8);
                const float mean = s * (1.f / 64.f);
                const float c0 = v0 - mean, c1 = v1 - mean, c2 = v2 - mean, c3 = v3 - mean;
                float q2 = c0 * c0 + c1 * c1 + c2 * c2 + c3 * c3;
                q2 += __shfl_xor(q2, 1); q2 += __shfl_xor(q2, 2);
                q2 += __shfl_xor(q2, 4); q2 += __shfl_xor(q2, 8);
                const float rs = rsqrtf(q2 * (1.f / 64.f) + 1e-5f);
                v0 = c0 * rs * gv[0] + bb[0];
                v1 = c1 * rs * gv[1] + bb[1];
                v2 = c2 * rs * gv[2] + bb[2];
                v3 = c3 * rs * gv[3] + bb[3];
                short* dst = (region == 0 ? Q : K) + ((size_t)(b_ * 12 + head) * 2048 + sg) * 64;
                dst[0 * 16 + lam] = f2bf(v0);
                dst[1 * 16 + lam] = f2bf(v1);
                dst[2 * 16 + lam] = f2bf(v2);
                dst[3 * 16 + lam] = f2bf(v3);
            } else {
                short* dst = Vt + (size_t)(b_ * 12 + head) * 64 * 2048 + sg;
                dst[(size_t)(0 * 16 + lam) * 2048] = f2bf(v0);
                dst[(size_t)(1 * 16 + lam) * 2048] = f2bf(v1);
                dst[(size_t)(2 * 16 + lam) * 2048] = f2bf(v2);
                dst[(size_t)(3 * 16 + lam) * 2048] = f2bf(v3);
            }
        }
    }
}

// ---------- flash attention: Q,K (B,H,2048,64) bf16; Vt (B,H,64,2048) bf16 ----------
// grid (32 q-blocks of 64 rows, 48 bh). Each wave: 16 q-rows, online softmax over
// K-tiles of 64. Output O (B, 2048, 768) bf16 (token-major for proj GEMM).

__global__ __launch_bounds__(256, 3) void attn(
    const short* __restrict__ Q, const short* __restrict__ K,
    const short* __restrict__ Vt, short* __restrict__ O)
{
    __shared__ __align__(16) short lP[4096];   // 4 waves x 16x64 bf16, chunk-interleaved
    const int tid  = threadIdx.x;
    const int w    = tid >> 6, lane = tid & 63;
    const int lam  = lane & 15, quad = lane >> 4;
    const int bh   = blockIdx.y;
    const int q0   = blockIdx.x * 64 + w * 16;
    const short* Qb = Q + (size_t)bh * 2048 * 64;
    const short* Kb = K + (size_t)bh * 2048 * 64;
    const short* Vb = Vt + (size_t)bh * 64 * 2048;
    short* myP = lP + w * 1024;

    s16x8 aq0 = *(const s16x8*)(Qb + (q0 + lam) * 64 + quad * 8);
    s16x8 aq1 = *(const s16x8*)(Qb + (q0 + lam) * 64 + 32 + quad * 8);

    const f32x4 fzero = {0.f, 0.f, 0.f, 0.f};
    float mr[4], lr[4];
    f32x4 o[4];
    #pragma unroll
    for (int r = 0; r < 4; r++) { mr[r] = -1e30f; lr[r] = 0.f; }
    #pragma unroll
    for (int t = 0; t < 4; t++) o[t] = fzero;

    for (int s0 = 0; s0 < 2048; s0 += 64) {
        // ---- scores: 16 x 64 ----
        f32x4 sc[4];
        #pragma unroll
        for (int t = 0; t < 4; t++) sc[t] = fzero;
        #pragma unroll
        for (int t = 0; t < 4; t++) {
            s16x8 kf0 = *(const s16x8*)(Kb + (s0 + t * 16 + lam) * 64 + quad * 8);
            s16x8 kf1 = *(const s16x8*)(Kb + (s0 + t * 16 + lam) * 64 + 32 + quad * 8);
            sc[t] = __builtin_amdgcn_mfma_f32_16x16x32_bf16(asbf(aq0), asbf(kf0), sc[t], 0, 0, 0);
            sc[t] = __builtin_amdgcn_mfma_f32_16x16x32_bf16(asbf(aq1), asbf(kf1), sc[t], 0, 0, 0);
        }
        #pragma unroll
        for (int t = 0; t < 4; t++) sc[t] *= 0.125f;   // 1/sqrt(64)

        // ---- online softmax update (rows live in 16-lane groups) ----
        #pragma unroll
        for (int r = 0; r < 4; r++) {
            float a = fmaxf(fmaxf(sc[0][r], sc[1][r]), fmaxf(sc[2][r], sc[3][r]));
            a = fmaxf(a, __shfl_xor(a, 1));
            a = fmaxf(a, __shfl_xor(a, 2));
            a = fmaxf(a, __shfl_xor(a, 4));
            a = fmaxf(a, __shfl_xor(a, 8));
            const float mn = fmaxf(mr[r], a);
            const float al = __expf(mr[r] - mn);
            mr[r] = mn;
            float rs = 0.f;
            #pragma unroll
            for (int t = 0; t < 4; t++) {
                const float p = __expf(sc[t][r] - mn);
                sc[t][r] = p;
                rs += p;
            }
            rs += __shfl_xor(rs, 1); rs += __shfl_xor(rs, 2);
            rs += __shfl_xor(rs, 4); rs += __shfl_xor(rs, 8);
            lr[r] = lr[r] * al + rs;
            #pragma unroll
            for (int t = 0; t < 4; t++) o[t][r] *= al;
        }

        // ---- P: C-layout -> A-operand layout via per-wave LDS ----
        #pragma unroll
        for (int t = 0; t < 4; t++) {
            const int col = t * 16 + lam;
            const int c2 = col >> 5, qq = (col >> 3) & 3, j = col & 7;
            #pragma unroll
            for (int r = 0; r < 4; r++) {
                const int row = quad * 4 + r;
                myP[((c2 * 4 + qq) * 16 + row) * 8 + j] = f2bf(sc[t][r]);
            }
        }
        s16x8 ap0 = *(const s16x8*)(myP + (quad * 16 + lam) * 8);
        s16x8 ap1 = *(const s16x8*)(myP + ((4 + quad) * 16 + lam) * 8);

        // ---- O += P @ V ----
        #pragma unroll
        for (int t = 0; t < 4; t++) {
            s16x8 vf0 = *(const s16x8*)(Vb + (t * 16 + lam) * 2048 + s0 + quad * 8);
            s16x8 vf1 = *(const s16x8*)(Vb + (t * 16 + lam) * 2048 + s0 + 32 + quad * 8);
            o[t] = __builtin_amdgcn_mfma_f32_16x16x32_bf16(asbf(ap0), asbf(vf0), o[t], 0, 0, 0);
            o[t] = __builtin_amdgcn_mfma_f32_16x16x32_bf16(asbf(ap1), asbf(vf1), o[t], 0, 0, 0);
        }
    }

    const int b_ = bh / 12, h_ = bh % 12;
    #pragma unroll
    for (int r = 0; r < 4; r++) {
        const float inv = 1.0f / lr[r];
        const int qg = q0 + quad * 4 + r;
        short* dst = O + ((size_t)(b_ * 2048 + qg)) * 768 + h_ * 64;
        #pragma unroll
        for (int t = 0; t < 4; t++) dst[t * 16 + lam] = f2bf(o[t][r] * inv);
    }
}

// ---------- proj GEMM (per stream: M=4096, N=768, K=768) + bias -> d_out fp32 ----------

__global__ __launch_bounds__(256, 2) void proj_gemm(
    const short* __restrict__ Ob,
    const short* __restrict__ Wpx, const short* __restrict__ Wpy,
    const float* __restrict__ bpx, const float* __restrict__ bpy,
    float* __restrict__ out)
{
    __shared__ __align__(16) short lA[8192];
    __shared__ __align__(16) short lB[8192];
    const int tid  = threadIdx.x;
    const int w    = tid >> 6, lane = tid & 63;
    const int lam  = lane & 15, quad = lane >> 4;
    const int strm = blockIdx.z;
    const short* W    = strm ? Wpy : Wpx;
    const float* bias = strm ? bpy : bpx;
    const int m0 = blockIdx.x * 128;
    const int n0 = blockIdx.y * 128;
    const int wm = w >> 1, wn = w & 1;

    const f32x4 fzero = {0.f, 0.f, 0.f, 0.f};
    f32x4 acc[4][4];
    #pragma unroll
    for (int i = 0; i < 4; i++)
        #pragma unroll
        for (int t = 0; t < 4; t++) acc[i][t] = fzero;

    for (int kb = 0; kb < 12; ++kb) {
        const int k0 = kb * 64;
        __syncthreads();
        #pragma unroll
        for (int c = 0; c < 2; c++) {
            #pragma unroll
            for (int h = 0; h < 2; h++) {
                const int ig = w + h * 4;
                const int r  = m0 + ig * 16 + lam;                       // per-stream token
                const int orow = ((r >> 10) * 2048) + (r & 1023) + strm * 1024;
                gl_lds16(Ob + (size_t)orow * 768 + k0 + c * 32 + quad * 8,
                         lA + (c * 8 + ig) * 512);
                gl_lds16(W + (size_t)(n0 + ig * 16 + lam) * 768 + k0 + c * 32 + quad * 8,
                         lB + (c * 8 + ig) * 512);
            }
        }
        __syncthreads();
        s16x8 af[2][4], bfr[2][4];
        #pragma unroll
        for (int c = 0; c < 2; c++)
            #pragma unroll
            for (int i = 0; i < 4; i++)
                af[c][i] = *(const s16x8*)(lA + ((c * 8 + wm * 4 + i) * 64 + lane) * 8);
        #pragma unroll
        for (int c = 0; c < 2; c++)
            #pragma unroll
            for (int t = 0; t < 4; t++)
                bfr[c][t] = *(const s16x8*)(lB + ((c * 8 + wn * 4 + t) * 64 + lane) * 8);
        #pragma unroll
        for (int c = 0; c < 2; c++)
            #pragma unroll
            for (int i = 0; i < 4; i++)
                #pragma unroll
                for (int t = 0; t < 4; t++)
                    acc[i][t] = __builtin_amdgcn_mfma_f32_16x16x32_bf16(
                        asbf(af[c][i]), asbf(bfr[c][t]), acc[i][t], 0, 0, 0);
    }

    const int nb = n0 + wn * 64;
    float bv[4];
    #pragma unroll
    for (int t = 0; t < 4; t++) bv[t] = bias[nb + t * 16 + lam];
    #pragma unroll
    for (int i = 0; i < 4; i++) {
        #pragma unroll
        for (int reg = 0; reg < 4; reg++) {
            const int mg = m0 + wm * 64 + i * 16 + quad * 4 + reg;
            float* dst = out + (size_t)strm * 3145728 + (size_t)mg * 768 + nb;
            #pragma unroll
            for (int t = 0; t < 4; t++) dst[t * 16 + lam] = acc[i][t][reg] + bv[t];
        }
    }
}

// ---------- launch ----------

#define WS_XBF 0
#define WS_YBF 6291456
#define WS_WQX 12582912
#define WS_WQY 16121856
#define WS_WPX 19660800
#define WS_WPY 20840448
#define WS_Q   22020096
#define WS_K   34603008
#define WS_VT  47185920
#define WS_O   59768832
// total 72351744 bytes

extern "C" void kernel_launch(void* const* d_in, const int* in_sizes, int n_in,
                              void* d_out, int out_size, void* d_ws, size_t ws_size,
                              hipStream_t stream) {
    (void)in_sizes; (void)n_in; (void)out_size; (void)ws_size;
    const float* x       = (const float*)d_in[0];
    const float* y       = (const float*)d_in[1];
    const float* Wqkv_x  = (const float*)d_in[2];
    const float* bqkv_x  = (const float*)d_in[3];
    const float* Wqkv_y  = (const float*)d_in[4];
    const float* bqkv_y  = (const float*)d_in[5];
    const float* Wproj_x = (const float*)d_in[6];
    const float* bproj_x = (const float*)d_in[7];
    const float* Wproj_y = (const float*)d_in[8];
    const float* bproj_y = (const float*)d_in[9];
    const float* gq_x = (const float*)d_in[10];
    const float* bq_x = (const float*)d_in[11];
    const float* gk_x = (const float*)d_in[12];
    const float* bk_x = (const float*)d_in[13];
    const float* gq_y = (const float*)d_in[14];
    const float* bq_y = (const float*)d_in[15];
    const float* gk_y = (const float*)d_in[16];
    const float* bk_y = (const float*)d_in[17];

    char* ws = (char*)d_ws;
    short* xbf = (short*)(ws + WS_XBF);
    short* ybf = (short*)(ws + WS_YBF);
    short* wqx = (short*)(ws + WS_WQX);
    short* wqy = (short*)(ws + WS_WQY);
    short* wpx = (short*)(ws + WS_WPX);
    short* wpy = (short*)(ws + WS_WPY);
    short* Qb  = (short*)(ws + WS_Q);
    short* Kb  = (short*)(ws + WS_K);
    short* Vtb = (short*)(ws + WS_VT);
    short* Ob  = (short*)(ws + WS_O);

    convert_all<<<10752, 256, 0, stream>>>(x, xbf, y, ybf, Wqkv_x, wqx,
                                           Wqkv_y, wqy, Wproj_x, wpx, Wproj_y, wpy);

    dim3 g1(32, 18, 2);
    qkv_gemm<<<g1, 256, 0, stream>>>(xbf, ybf, wqx, wqy, bqkv_x, bqkv_y,
                                     gq_x, bq_x, gk_x, bk_x,
                                     gq_y, bq_y, gk_y, bk_y,
                                     Qb, Kb, Vtb);

    dim3 g2(32, 48);
    attn<<<g2, 256, 0, stream>>>(Qb, Kb, Vtb, Ob);

    dim3 g3(32, 6, 2);
    proj_gemm<<<g3, 256, 0, stream>>>(Ob, wpx, wpy, bproj_x, bproj_y, (float*)d_out);
}

// Round 2
// 309.214 us; speedup vs baseline: 1.8286x; 1.8286x over previous
//
#include <hip/hip_runtime.h>
#include <stdint.h>

typedef unsigned int u32;
typedef __attribute__((ext_vector_type(8))) __bf16 bf16x8;
typedef __attribute__((ext_vector_type(8))) short s16x8;
typedef __attribute__((ext_vector_type(4))) short s16x4;
typedef __attribute__((ext_vector_type(4))) float f32x4;

// ---------- helpers ----------

__device__ __forceinline__ short f2bf(float f) {
    __bf16 h = (__bf16)f;               // native v_cvt, RNE
    return __builtin_bit_cast(short, h);
}

__device__ __forceinline__ bf16x8 asbf(s16x8 v) {
    return __builtin_bit_cast(bf16x8, v);
}

// async global->LDS, 16B per lane. LDS dest = wave-uniform base + lane*16.
__device__ __forceinline__ void gl_lds16(const void* g, void* l) {
    __builtin_amdgcn_global_load_lds((__attribute__((address_space(1))) u32*)g,
                                     (__attribute__((address_space(3))) u32*)l,
                                     16, 0, 0);
}

// ---------- conversion kernel: fp32 -> bf16 for x, y, Wqkv_x, Wqkv_y, Wproj_x, Wproj_y ----------

__global__ __launch_bounds__(256) void convert_all(
    const float* __restrict__ s0, short* __restrict__ d0,
    const float* __restrict__ s1, short* __restrict__ d1,
    const float* __restrict__ s2, short* __restrict__ d2,
    const float* __restrict__ s3, short* __restrict__ d3,
    const float* __restrict__ s4, short* __restrict__ d4,
    const float* __restrict__ s5, short* __restrict__ d5)
{
    int i = blockIdx.x * 256 + threadIdx.x;   // one float4 per thread
    const float* s; short* d;
    if (i < 786432)                { s = s0; d = d0; }
    else if ((i -= 786432) < 786432) { s = s1; d = d1; }
    else if ((i -= 786432) < 442368) { s = s2; d = d2; }
    else if ((i -= 442368) < 442368) { s = s3; d = d3; }
    else if ((i -= 442368) < 147456) { s = s4; d = d4; }
    else                           { i -= 147456; s = s5; d = d5; }
    f32x4 v = ((const f32x4*)s)[i];
    s16x4 o;
    o.x = f2bf(v.x); o.y = f2bf(v.y); o.z = f2bf(v.z); o.w = f2bf(v.w);
    ((s16x4*)d)[i] = o;
}

// ---------- QKV GEMM (M=4096, N=2304, K=768) + bias + fused per-head LN ----------

__global__ __launch_bounds__(256, 2) void qkv_gemm(
    const short* __restrict__ Ax, const short* __restrict__ Ay,
    const short* __restrict__ Wx, const short* __restrict__ Wy,
    const float* __restrict__ biasx, const float* __restrict__ biasy,
    const float* __restrict__ gqx, const float* __restrict__ bqx,
    const float* __restrict__ gkx, const float* __restrict__ bkx,
    const float* __restrict__ gqy, const float* __restrict__ bqy,
    const float* __restrict__ gky, const float* __restrict__ bky,
    short* __restrict__ Q, short* __restrict__ K, short* __restrict__ Vt)
{
    __shared__ __align__(16) short lA[8192];   // 128x64 bf16, chunk-interleaved
    __shared__ __align__(16) short lB[8192];
    const int tid  = threadIdx.x;
    const int w    = tid >> 6, lane = tid & 63;
    const int lam  = lane & 15, quad = lane >> 4;
    const int strm = blockIdx.z;
    const short* A    = strm ? Ay : Ax;
    const short* W    = strm ? Wy : Wx;
    const float* bias = strm ? biasy : biasx;
    const int m0 = blockIdx.x * 128;
    const int n0 = blockIdx.y * 128;
    const int wm = w >> 1, wn = w & 1;

    const f32x4 fzero = {0.f, 0.f, 0.f, 0.f};
    f32x4 acc[4][4];
    #pragma unroll
    for (int i = 0; i < 4; i++)
        #pragma unroll
        for (int t = 0; t < 4; t++) acc[i][t] = fzero;

    for (int kb = 0; kb < 12; ++kb) {
        const int k0 = kb * 64;
        __syncthreads();
        #pragma unroll
        for (int c = 0; c < 2; c++) {
            #pragma unroll
            for (int h = 0; h < 2; h++) {
                const int ig = w + h * 4;
                gl_lds16(A + (size_t)(m0 + ig * 16 + lam) * 768 + k0 + c * 32 + quad * 8,
                         lA + (c * 8 + ig) * 512);
                gl_lds16(W + (size_t)(n0 + ig * 16 + lam) * 768 + k0 + c * 32 + quad * 8,
                         lB + (c * 8 + ig) * 512);
            }
        }
        __syncthreads();
        s16x8 af[2][4], bfr[2][4];
        #pragma unroll
        for (int c = 0; c < 2; c++)
            #pragma unroll
            for (int i = 0; i < 4; i++)
                af[c][i] = *(const s16x8*)(lA + ((c * 8 + wm * 4 + i) * 64 + lane) * 8);
        #pragma unroll
        for (int c = 0; c < 2; c++)
            #pragma unroll
            for (int t = 0; t < 4; t++)
                bfr[c][t] = *(const s16x8*)(lB + ((c * 8 + wn * 4 + t) * 64 + lane) * 8);
        #pragma unroll
        for (int c = 0; c < 2; c++)
            #pragma unroll
            for (int i = 0; i < 4; i++)
                #pragma unroll
                for (int t = 0; t < 4; t++)
                    acc[i][t] = __builtin_amdgcn_mfma_f32_16x16x32_bf16(
                        asbf(af[c][i]), asbf(bfr[c][t]), acc[i][t], 0, 0, 0);
    }

    const int nb     = n0 + wn * 64;
    const int region = nb / 768;               // 0=q, 1=k, 2=v
    const int head   = (nb % 768) / 64;
    float bv[4];
    #pragma unroll
    for (int t = 0; t < 4; t++) bv[t] = bias[nb + t * 16 + lam];
    float gv[4], bb[4];
    if (region < 2) {
        const float* gp = (region == 0) ? (strm ? gqy : gqx) : (strm ? gky : gkx);
        const float* bp = (region == 0) ? (strm ? bqy : bqx) : (strm ? bky : bkx);
        #pragma unroll
        for (int t = 0; t < 4; t++) { gv[t] = gp[t * 16 + lam]; bb[t] = bp[t * 16 + lam]; }
    }

    #pragma unroll
    for (int i = 0; i < 4; i++) {
        #pragma unroll
        for (int reg = 0; reg < 4; reg++) {
            const int mg = m0 + wm * 64 + i * 16 + quad * 4 + reg;
            const int b_ = mg >> 10;
            const int sg = (mg & 1023) + strm * 1024;
            float v0 = acc[i][0][reg] + bv[0];
            float v1 = acc[i][1][reg] + bv[1];
            float v2 = acc[i][2][reg] + bv[2];
            float v3 = acc[i][3][reg] + bv[3];
            if (region < 2) {
                float s = v0 + v1 + v2 + v3;
                s += __shfl_xor(s, 1); s += __shfl_xor(s, 2);
                s += __shfl_xor(s, 4); s += __shfl_xor(s, 8);
                const float mean = s * (1.f / 64.f);
                const float c0 = v0 - mean, c1 = v1 - mean, c2 = v2 - mean, c3 = v3 - mean;
                float q2 = c0 * c0 + c1 * c1 + c2 * c2 + c3 * c3;
                q2 += __shfl_xor(q2, 1); q2 += __shfl_xor(q2, 2);
                q2 += __shfl_xor(q2, 4); q2 += __shfl_xor(q2, 8);
                const float rs = rsqrtf(q2 * (1.f / 64.f) + 1e-5f);
                v0 = c0 * rs * gv[0] + bb[0];
                v1 = c1 * rs * gv[1] + bb[1];
                v2 = c2 * rs * gv[2] + bb[2];
                v3 = c3 * rs * gv[3] + bb[3];
                short* dst = (region == 0 ? Q : K) + ((size_t)(b_ * 12 + head) * 2048 + sg) * 64;
                dst[0 * 16 + lam] = f2bf(v0);
                dst[1 * 16 + lam] = f2bf(v1);
                dst[2 * 16 + lam] = f2bf(v2);
                dst[3 * 16 + lam] = f2bf(v3);
            } else {
                short* dst = Vt + (size_t)(b_ * 12 + head) * 64 * 2048 + sg;
                dst[(size_t)(0 * 16 + lam) * 2048] = f2bf(v0);
                dst[(size_t)(1 * 16 + lam) * 2048] = f2bf(v1);
                dst[(size_t)(2 * 16 + lam) * 2048] = f2bf(v2);
                dst[(size_t)(3 * 16 + lam) * 2048] = f2bf(v3);
            }
        }
    }
}

// ---------- flash attention v2 ----------
// grid (48 bh, 16 q-blocks). Block: 4 waves, 128 q-rows (32/wave).
// K/V tiles (64 x 64 bf16 each) staged in LDS via global_load_lds, double-buffered,
// ONE barrier per iteration (prefetch issued right after the barrier).
// Max-free online softmax: p = exp2(score*log2e - 30); l reduced once at the end.

__global__ __launch_bounds__(256, 3) void attn(
    const short* __restrict__ Q, const short* __restrict__ K,
    const short* __restrict__ Vt, short* __restrict__ O)
{
    __shared__ __align__(16) short lK[2][4096];   // 8 KB per buffer
    __shared__ __align__(16) short lV[2][4096];
    __shared__ __align__(16) short lP[4][1088];   // per-wave P, pad: block stride 17
    const int tid  = threadIdx.x;
    const int w    = tid >> 6, lane = tid & 63;
    const int lam  = lane & 15, quad = lane >> 4;
    const int bh   = blockIdx.x;                  // fast dim: same bh -> same XCD
    const int q0   = blockIdx.y * 128 + w * 32;
    const short* Qb = Q + (size_t)bh * 2048 * 64;
    const short* Kb = K + (size_t)bh * 2048 * 64;
    const short* Vb = Vt + (size_t)bh * 64 * 2048;
    short* myP = lP[w];

    // Q fragments: 2 q-tiles x 2 k-chunks, resident in registers
    s16x8 aq[2][2];
    #pragma unroll
    for (int qf = 0; qf < 2; qf++)
        #pragma unroll
        for (int c = 0; c < 2; c++)
            aq[qf][c] = *(const s16x8*)(Qb + (size_t)(q0 + qf * 16 + lam) * 64 + c * 32 + quad * 8);

    const f32x4 fzero = {0.f, 0.f, 0.f, 0.f};
    f32x4 o[2][4];
    float lsum[2][4];
    #pragma unroll
    for (int qf = 0; qf < 2; qf++) {
        #pragma unroll
        for (int t = 0; t < 4; t++) o[qf][t] = fzero;
        #pragma unroll
        for (int r = 0; r < 4; r++) lsum[qf][r] = 0.f;
    }

    // stage tile s0 into buffer bi: 16 x 1KB DMA calls spread over 4 waves
    #define STAGE(s0_, bi_)                                                              \
        do {                                                                             \
            gl_lds16(Kb + (size_t)((s0_) + w * 16 + lam) * 64 + quad * 8,                \
                     &lK[bi_][(0 * 4 + w) * 512]);                                       \
            gl_lds16(Kb + (size_t)((s0_) + w * 16 + lam) * 64 + 32 + quad * 8,           \
                     &lK[bi_][(1 * 4 + w) * 512]);                                       \
            gl_lds16(Vb + (size_t)(w * 16 + lam) * 2048 + (s0_) + quad * 8,              \
                     &lV[bi_][(0 * 4 + w) * 512]);                                       \
            gl_lds16(Vb + (size_t)(w * 16 + lam) * 2048 + (s0_) + 32 + quad * 8,         \
                     &lV[bi_][(1 * 4 + w) * 512]);                                       \
        } while (0)

    STAGE(0, 0);
    __syncthreads();                 // tile 0 ready (barrier drains vmcnt)

    const float c1 = 0.18033688011112042f;   // 0.125 * log2(e)
    int bi = 0;
    for (int it = 0; it < 32; ++it) {
        const int s0n = (it + 1) * 64;
        if (s0n < 2048) STAGE(s0n, bi ^ 1);  // async prefetch, lands during compute

        const short* cK = lK[bi];
        const short* cV = lV[bi];
        #pragma unroll
        for (int qf = 0; qf < 2; qf++) {
            // ---- scores: 16 x 64 ----
            f32x4 sc[4];
            #pragma unroll
            for (int t = 0; t < 4; t++) sc[t] = fzero;
            #pragma unroll
            for (int t = 0; t < 4; t++) {
                s16x8 k0 = *(const s16x8*)(cK + ((0 * 4 + t) * 512 + lane * 8));
                s16x8 k1 = *(const s16x8*)(cK + ((1 * 4 + t) * 512 + lane * 8));
                sc[t] = __builtin_amdgcn_mfma_f32_16x16x32_bf16(asbf(aq[qf][0]), asbf(k0), sc[t], 0, 0, 0);
                sc[t] = __builtin_amdgcn_mfma_f32_16x16x32_bf16(asbf(aq[qf][1]), asbf(k1), sc[t], 0, 0, 0);
            }
            // ---- p = exp2(s*c1 - 30), accumulate l, pack to LDS (A-layout, padded) ----
            #pragma unroll
            for (int t = 0; t < 4; t++) {
                const int g = t * 2 + (lam >> 3);
                #pragma unroll
                for (int r = 0; r < 4; r++) {
                    const float p = __builtin_amdgcn_exp2f(__builtin_fmaf(sc[t][r], c1, -30.f));
                    lsum[qf][r] += p;
                    myP[(g * 17 + quad * 4 + r) * 8 + (lam & 7)] = f2bf(p);
                }
            }
            s16x8 ap0 = *(const s16x8*)(myP + (quad * 17 + lam) * 8);
            s16x8 ap1 = *(const s16x8*)(myP + ((4 + quad) * 17 + lam) * 8);
            // ---- O += P @ V ----
            #pragma unroll
            for (int t = 0; t < 4; t++) {
                s16x8 v0 = *(const s16x8*)(cV + ((0 * 4 + t) * 512 + lane * 8));
                s16x8 v1 = *(const s16x8*)(cV + ((1 * 4 + t) * 512 + lane * 8));
                o[qf][t] = __builtin_amdgcn_mfma_f32_16x16x32_bf16(asbf(ap0), asbf(v0), o[qf][t], 0, 0, 0);
                o[qf][t] = __builtin_amdgcn_mfma_f32_16x16x32_bf16(asbf(ap1), asbf(v1), o[qf][t], 0, 0, 0);
            }
        }
        __syncthreads();             // drains prefetch; protects buffer reuse
        bi ^= 1;
    }
    #undef STAGE

    const int b_ = bh / 12, h_ = bh % 12;
    #pragma unroll
    for (int qf = 0; qf < 2; qf++) {
        #pragma unroll
        for (int r = 0; r < 4; r++) {
            float l = lsum[qf][r];
            l += __shfl_xor(l, 1); l += __shfl_xor(l, 2);
            l += __shfl_xor(l, 4); l += __shfl_xor(l, 8);
            const float inv = 1.0f / l;
            const int qg = q0 + qf * 16 + quad * 4 + r;
            short* dst = O + ((size_t)(b_ * 2048 + qg)) * 768 + h_ * 64;
            #pragma unroll
            for (int t = 0; t < 4; t++) dst[t * 16 + lam] = f2bf(o[qf][t][r] * inv);
        }
    }
}

// ---------- proj GEMM (per stream: M=4096, N=768, K=768) + bias -> d_out fp32 ----------

__global__ __launch_bounds__(256, 2) void proj_gemm(
    const short* __restrict__ Ob,
    const short* __restrict__ Wpx, const short* __restrict__ Wpy,
    const float* __restrict__ bpx, const float* __restrict__ bpy,
    float* __restrict__ out)
{
    __shared__ __align__(16) short lA[8192];
    __shared__ __align__(16) short lB[8192];
    const int tid  = threadIdx.x;
    const int w    = tid >> 6, lane = tid & 63;
    const int lam  = lane & 15, quad = lane >> 4;
    const int strm = blockIdx.z;
    const short* W    = strm ? Wpy : Wpx;
    const float* bias = strm ? bpy : bpx;
    const int m0 = blockIdx.x * 128;
    const int n0 = blockIdx.y * 128;
    const int wm = w >> 1, wn = w & 1;

    const f32x4 fzero = {0.f, 0.f, 0.f, 0.f};
    f32x4 acc[4][4];
    #pragma unroll
    for (int i = 0; i < 4; i++)
        #pragma unroll
        for (int t = 0; t < 4; t++) acc[i][t] = fzero;

    for (int kb = 0; kb < 12; ++kb) {
        const int k0 = kb * 64;
        __syncthreads();
        #pragma unroll
        for (int c = 0; c < 2; c++) {
            #pragma unroll
            for (int h = 0; h < 2; h++) {
                const int ig = w + h * 4;
                const int r  = m0 + ig * 16 + lam;
                const int orow = ((r >> 10) * 2048) + (r & 1023) + strm * 1024;
                gl_lds16(Ob + (size_t)orow * 768 + k0 + c * 32 + quad * 8,
                         lA + (c * 8 + ig) * 512);
                gl_lds16(W + (size_t)(n0 + ig * 16 + lam) * 768 + k0 + c * 32 + quad * 8,
                         lB + (c * 8 + ig) * 512);
            }
        }
        __syncthreads();
        s16x8 af[2][4], bfr[2][4];
        #pragma unroll
        for (int c = 0; c < 2; c++)
            #pragma unroll
            for (int i = 0; i < 4; i++)
                af[c][i] = *(const s16x8*)(lA + ((c * 8 + wm * 4 + i) * 64 + lane) * 8);
        #pragma unroll
        for (int c = 0; c < 2; c++)
            #pragma unroll
            for (int t = 0; t < 4; t++)
                bfr[c][t] = *(const s16x8*)(lB + ((c * 8 + wn * 4 + t) * 64 + lane) * 8);
        #pragma unroll
        for (int c = 0; c < 2; c++)
            #pragma unroll
            for (int i = 0; i < 4; i++)
                #pragma unroll
                for (int t = 0; t < 4; t++)
                    acc[i][t] = __builtin_amdgcn_mfma_f32_16x16x32_bf16(
                        asbf(af[c][i]), asbf(bfr[c][t]), acc[i][t], 0, 0, 0);
    }

    const int nb = n0 + wn * 64;
    float bv[4];
    #pragma unroll
    for (int t = 0; t < 4; t++) bv[t] = bias[nb + t * 16 + lam];
    #pragma unroll
    for (int i = 0; i < 4; i++) {
        #pragma unroll
        for (int reg = 0; reg < 4; reg++) {
            const int mg = m0 + wm * 64 + i * 16 + quad * 4 + reg;
            float* dst = out + (size_t)strm * 3145728 + (size_t)mg * 768 + nb;
            #pragma unroll
            for (int t = 0; t < 4; t++) dst[t * 16 + lam] = acc[i][t][reg] + bv[t];
        }
    }
}

// ---------- launch ----------

#define WS_XBF 0
#define WS_YBF 6291456
#define WS_WQX 12582912
#define WS_WQY 16121856
#define WS_WPX 19660800
#define WS_WPY 20840448
#define WS_Q   22020096
#define WS_K   34603008
#define WS_VT  47185920
#define WS_O   59768832

extern "C" void kernel_launch(void* const* d_in, const int* in_sizes, int n_in,
                              void* d_out, int out_size, void* d_ws, size_t ws_size,
                              hipStream_t stream) {
    (void)in_sizes; (void)n_in; (void)out_size; (void)ws_size;
    const float* x       = (const float*)d_in[0];
    const float* y       = (const float*)d_in[1];
    const float* Wqkv_x  = (const float*)d_in[2];
    const float* bqkv_x  = (const float*)d_in[3];
    const float* Wqkv_y  = (const float*)d_in[4];
    const float* bqkv_y  = (const float*)d_in[5];
    const float* Wproj_x = (const float*)d_in[6];
    const float* bproj_x = (const float*)d_in[7];
    const float* Wproj_y = (const float*)d_in[8];
    const float* bproj_y = (const float*)d_in[9];
    const float* gq_x = (const float*)d_in[10];
    const float* bq_x = (const float*)d_in[11];
    const float* gk_x = (const float*)d_in[12];
    const float* bk_x = (const float*)d_in[13];
    const float* gq_y = (const float*)d_in[14];
    const float* bq_y = (const float*)d_in[15];
    const float* gk_y = (const float*)d_in[16];
    const float* bk_y = (const float*)d_in[17];

    char* ws = (char*)d_ws;
    short* xbf = (short*)(ws + WS_XBF);
    short* ybf = (short*)(ws + WS_YBF);
    short* wqx = (short*)(ws + WS_WQX);
    short* wqy = (short*)(ws + WS_WQY);
    short* wpx = (short*)(ws + WS_WPX);
    short* wpy = (short*)(ws + WS_WPY);
    short* Qb  = (short*)(ws + WS_Q);
    short* Kb  = (short*)(ws + WS_K);
    short* Vtb = (short*)(ws + WS_VT);
    short* Ob  = (short*)(ws + WS_O);

    convert_all<<<10752, 256, 0, stream>>>(x, xbf, y, ybf, Wqkv_x, wqx,
                                           Wqkv_y, wqy, Wproj_x, wpx, Wproj_y, wpy);

    dim3 g1(32, 18, 2);
    qkv_gemm<<<g1, 256, 0, stream>>>(xbf, ybf, wqx, wqy, bqkv_x, bqkv_y,
                                     gq_x, bq_x, gk_x, bk_x,
                                     gq_y, bq_y, gk_y, bk_y,
                                     Qb, Kb, Vtb);

    dim3 g2(48, 16);
    attn<<<g2, 256, 0, stream>>>(Qb, Kb, Vtb, Ob);

    dim3 g3(32, 6, 2);
    proj_gemm<<<g3, 256, 0, stream>>>(Ob, wpx, wpy, bproj_x, bproj_y, (float*)d_out);
}